// Round 12
// baseline (127.575 us; speedup 1.0000x reference)
//
#include <hip/hip_runtime.h>
#include <hip/hip_bf16.h>
#include <string.h>

#define NTOK 64
#define HEADS 8
#define SKV 136   // K/V stage row stride (ushorts) = 272 B
#define SO2 132   // O-stage row stride (ushorts, bf16) = 264 B

typedef __attribute__((ext_vector_type(4))) float f32x4;
typedef __attribute__((ext_vector_type(2))) unsigned int u32x2;
typedef __attribute__((ext_vector_type(4))) unsigned int u32x4;
typedef __attribute__((ext_vector_type(8))) short bf16x8;

__device__ float g_bias225[225 * 8];   // overwritten fully every launch (deterministic)

// packed f32x2 -> bf16x2 (RNE) -- v_cvt_pk_bf16_f32
__device__ __forceinline__ unsigned int cvt2(float a, float b) {
    __hip_bfloat162 h = __float22bfloat162_rn(float2{a, b});
    unsigned int r;
    memcpy(&r, &h, 4);
    return r;
}

// Stage 1: MLP over the 225 distinct relative positions. One wave per pair.
__global__ __launch_bounds__(64) void mlp_pairs_kernel(
    const float* __restrict__ w1, const float* __restrict__ b1,
    const float* __restrict__ w2, const float* __restrict__ b2)
{
    int pair = blockIdx.x;
    int lane = threadIdx.x;
    int dy = pair / 15 - 7;
    int dx = pair % 15 - 7;
    float fy = copysignf(log1pf(fabsf((float)dy)), (float)dy);
    float fx = copysignf(log1pf(fabsf((float)dx)), (float)dx);
    int h = lane & 7;
    int j0 = lane >> 3;
    float acc = 0.0f;
    #pragma unroll 4
    for (int i = 0; i < 32; ++i) {
        int j = j0 + 8 * i;
        float t = fy * w1[j] + fx * w1[256 + j] + b1[j];
        float ge = 0.5f * t * (1.0f + erff(t * 0.70710678118654752f)); // exact GELU
        acc = fmaf(ge, w2[j * HEADS + h], acc);
    }
    acc += __shfl_xor(acc, 8, 64);
    acc += __shfl_xor(acc, 16, 64);
    acc += __shfl_xor(acc, 32, 64);
    if (lane < 8)
        g_bias225[pair * 8 + lane] = (acc + b2[lane]) * 1.44269504088896341f; // fold log2(e)
}

// Stage 2: scatter bias225 -> fragment-layout table
__global__ __launch_bounds__(256) void bias_scatter_kernel(float* __restrict__ bias_ws)
{
    int idx = blockIdx.x * 256 + threadIdx.x;   // 32768 total
    int r  = idx & 3;
    int l  = (idx >> 2) & 63;
    int nt = (idx >> 8) & 3;
    int mt = (idx >> 10) & 3;
    int h  = idx >> 12;
    int n = nt * 16 + (l & 15);
    int m = mt * 16 + (l >> 4) * 4 + r;
    int pair = ((n >> 3) - (m >> 3) + 7) * 15 + ((n & 7) - (m & 7) + 7);
    bias_ws[idx] = g_bias225[pair * 8 + h];
}

// Block = 4 heads of one window. K,V staged block-cooperatively; Q direct with
// per-strip prefetch; O staged in LDS as bf16 and stored block-cooperatively.
// LDS 35.3 KB -> 4 blocks/CU (was 3): higher HBM duty cycle across phases.
__global__ __launch_bounds__(256, 4) void win_attn_kernel(
    const float* __restrict__ qkv,
    const float* __restrict__ bias_ws,
    float* __restrict__ out)
{
    // phase 1 (stage):  [0,17408) K | [17408,34816) V
    // phase 2 (strips): [0,18432) P dbuf (4 waves x 4608) | [18432,35328) O stage bf16 [64][SO2]
    __shared__ __align__(16) unsigned char lds_all[35328];
    unsigned short* lds_k = (unsigned short*)lds_all;
    unsigned short* lds_v = (unsigned short*)(lds_all + 17408);
    unsigned short (*lds_p)[16][72] = (unsigned short (*)[16][72])(lds_all + (threadIdx.x >> 6) * 4608);
    unsigned short* ostage = (unsigned short*)(lds_all + 18432);

    const int tid = threadIdx.x;
    const int w = tid >> 6;
    const int l = tid & 63;
    const int c = l & 15;
    const int g = l >> 4;
    const int half = blockIdx.x & 1;
    const int b = blockIdx.x >> 1;
    const int h = half * 4 + w;                      // this wave's head
    const float* wbase = qkv + (size_t)b * (NTOK * 768);
    const float QS = 0.176776695296636893f * 1.44269504088896341f; // scale * log2(e)

    // ---- block-cooperative staging of K,V (4-head slices, bf16): 512-B segments ----
    {
        const int srow0 = tid >> 5;
        const int scol  = (tid & 31) * 4;
        #pragma unroll
        for (int i = 0; i < 8; ++i) {
            int row = i * 8 + srow0;
            const float* pr = wbase + (size_t)row * 768 + half * 128 + scol;
            f32x4 kk = *(const f32x4*)(pr + 256);
            f32x4 vv = *(const f32x4*)(pr + 512);
            u32x2 kw = {cvt2(kk[0], kk[1]), cvt2(kk[2], kk[3])};
            u32x2 vw = {cvt2(vv[0], vv[1]), cvt2(vv[2], vv[3])};
            *(u32x2*)(lds_k + row * SKV + scol) = kw;
            *(u32x2*)(lds_v + row * SKV + scol) = vw;
        }
    }
    __syncthreads();

    // ---- K A-frags from LDS (b128) ----
    bf16x8 kf[4];
    #pragma unroll
    for (int t = 0; t < 4; ++t)
        kf[t] = *(const bf16x8*)(lds_k + (t * 16 + c) * SKV + w * 32 + g * 8);

    // ---- V^T A-frags: column reads (u16, once per wave) ----
    bf16x8 vf[2][2];
    #pragma unroll
    for (int ks = 0; ks < 2; ++ks)
        #pragma unroll
        for (int dt = 0; dt < 2; ++dt) {
            bf16x8 v;
            #pragma unroll
            for (int j = 0; j < 8; ++j)
                v[j] = (short)lds_v[(ks * 32 + g * 8 + j) * SKV + w * 32 + dt * 16 + c];
            vf[ks][dt] = v;
        }
    __syncthreads();   // stage regions now dead -> overlay with P dbuf + O stage

    // Q strip 0 raw (direct; per-strip prefetch below keeps HBM busy during strips)
    const float* qb = wbase + h * 32;
    f32x4 qraw0, qraw1;
    {
        const float* pq = qb + (size_t)c * 768 + g * 8;
        qraw0 = *(const f32x4*)(pq);
        qraw1 = *(const f32x4*)(pq + 4);
    }

    // ---- strip loop over n (nt): S^T strip -> exp2 -> P -> O^T strip -> LDS O-stage ----
    #pragma unroll
    for (int nt = 0; nt < 4; ++nt) {
        bf16x8 qf;
        {
            u32x4 qq = {cvt2(qraw0[0] * QS, qraw0[1] * QS), cvt2(qraw0[2] * QS, qraw0[3] * QS),
                        cvt2(qraw1[0] * QS, qraw1[1] * QS), cvt2(qraw1[2] * QS, qraw1[3] * QS)};
            memcpy(&qf, &qq, 16);
        }

        // S^T strip = K.Q^T seeded with bias frags (C-operand; L2-resident table)
        f32x4 acc[4];
        {
            const f32x4* bw = (const f32x4*)(bias_ws) + ((size_t)h * 16 + nt) * 64 + l;
            #pragma unroll
            for (int mt = 0; mt < 4; ++mt)
                acc[mt] = bw[mt * 256];
        }
        #pragma unroll
        for (int mt = 0; mt < 4; ++mt)
            acc[mt] = __builtin_amdgcn_mfma_f32_16x16x32_bf16(kf[mt], qf, acc[mt], 0, 0, 0);

        // prefetch next strip's Q while MFMAs run
        if (nt < 3) {
            const float* pq = qb + (size_t)((nt + 1) * 16 + c) * 768 + g * 8;
            qraw0 = *(const f32x4*)(pq);
            qraw1 = *(const f32x4*)(pq + 4);
        }

        // softmax numerators, no max-subtract (bounded log2-unit scores; f32-safe)
        float s = 0.0f;
        #pragma unroll
        for (int mt = 0; mt < 4; ++mt)
            #pragma unroll
            for (int r = 0; r < 4; ++r) {
                float p = __builtin_amdgcn_exp2f(acc[mt][r]);
                acc[mt][r] = p;
                s += p;
            }

        // P strip (bf16, [n][m]) -> LDS (packed cvt + b64 writes, double-buffered)
        unsigned short (*P)[72] = lds_p[nt & 1];
        #pragma unroll
        for (int mt = 0; mt < 4; ++mt) {
            unsigned int w0 = cvt2(acc[mt][0], acc[mt][1]);
            unsigned int w1 = cvt2(acc[mt][2], acc[mt][3]);
            *(u32x2*)(&P[c][mt * 16 + g * 4]) = (u32x2){w0, w1};
        }

        // cross-lane sum finish + rcp (overlaps the fence drain)
        s += __shfl_xor(s, 16, 64);
        s += __shfl_xor(s, 32, 64);
        float iv = __builtin_amdgcn_rcpf(s);

        // order: P ds_writes visible before cross-lane ds_reads
        __threadfence_block();

        // O^T strip = V^T . P^T
        f32x4 o[2];
        o[0] = (f32x4){0.f, 0.f, 0.f, 0.f};
        o[1] = (f32x4){0.f, 0.f, 0.f, 0.f};
        #pragma unroll
        for (int ks = 0; ks < 2; ++ks) {
            bf16x8 pb = *(const bf16x8*)(&P[c][ks * 32 + g * 8]);
            #pragma unroll
            for (int dt = 0; dt < 2; ++dt)
                o[dt] = __builtin_amdgcn_mfma_f32_16x16x32_bf16(vf[ks][dt], pb, o[dt], 0, 0, 0);
        }

        // normalize + write to LDS O-stage bf16 [64][SO2] (col ranges disjoint per wave)
        #pragma unroll
        for (int dt = 0; dt < 2; ++dt) {
            u32x2 ow = {cvt2(o[dt][0] * iv, o[dt][1] * iv),
                        cvt2(o[dt][2] * iv, o[dt][3] * iv)};
            *(u32x2*)(ostage + (nt * 16 + c) * SO2 + w * 32 + dt * 16 + g * 4) = ow;
        }
    }
    __syncthreads();

    // ---- block-cooperative store: expand bf16 -> f32, 512-B contiguous per row ----
    {
        float* ob = out + (size_t)b * (NTOK * 256) + half * 128;
        const int srow0 = tid >> 5;
        const int scol  = (tid & 31) * 4;   // floats
        #pragma unroll
        for (int i = 0; i < 8; ++i) {
            int row = i * 8 + srow0;
            u32x2 pk = *(const u32x2*)(ostage + row * SO2 + scol);
            f32x4 val;
            val[0] = __uint_as_float((pk[0] & 0xFFFFu) << 16);
            val[1] = __uint_as_float(pk[0] & 0xFFFF0000u);
            val[2] = __uint_as_float((pk[1] & 0xFFFFu) << 16);
            val[3] = __uint_as_float(pk[1] & 0xFFFF0000u);
            *(f32x4*)(ob + (size_t)row * 256 + scol) = val;
        }
    }
}

extern "C" void kernel_launch(void* const* d_in, const int* in_sizes, int n_in,
                              void* d_out, int out_size, void* d_ws, size_t ws_size,
                              hipStream_t stream) {
    const float* qkv = (const float*)d_in[0];
    const float* w1  = (const float*)d_in[1];
    const float* b1  = (const float*)d_in[2];
    const float* w2  = (const float*)d_in[3];
    const float* b2  = (const float*)d_in[4];
    float* bias_ws = (float*)d_ws;   // 32768 floats = 128 KiB (proven size)

    mlp_pairs_kernel<<<225, 64, 0, stream>>>(w1, b1, w2, b2);
    bias_scatter_kernel<<<128, 256, 0, stream>>>(bias_ws);

    int B = in_sizes[0] / 49152;   // windows
    win_attn_kernel<<<B * 2, 256, 0, stream>>>(qkv, bias_ws, (float*)d_out);
}

// Round 13
// 124.111 us; speedup vs baseline: 1.0279x; 1.0279x over previous
//
#include <hip/hip_runtime.h>
#include <hip/hip_bf16.h>
#include <string.h>

#define NTOK 64
#define HEADS 8
#define SKV 136   // stage row stride (ushorts) = 272 B
#define SO  132   // O-stage row stride (floats) = 528 B -> 2-way-free banks

typedef __attribute__((ext_vector_type(4))) float f32x4;
typedef __attribute__((ext_vector_type(2))) unsigned int u32x2;
typedef __attribute__((ext_vector_type(8))) short bf16x8;

// packed f32x2 -> bf16x2 (RNE) -- v_cvt_pk_bf16_f32
__device__ __forceinline__ unsigned int cvt2(float a, float b) {
    __hip_bfloat162 h = __float22bfloat162_rn(float2{a, b});
    unsigned int r;
    memcpy(&r, &h, 4);
    return r;
}

// Fused prelude: one block per relative position (225). Computes the 2->256->8
// MLP for its (dy,dx), then scatters log2e*bias directly into the fragment-layout
// table bias_ws[h][mt][nt][lane][r] for every (n,m) with that offset.
// After the xor{8,16,32} reduce, EVERY lane holds the full sum for h = lane&7.
__global__ __launch_bounds__(64) void mlp_bias_kernel(
    const float* __restrict__ w1, const float* __restrict__ b1,
    const float* __restrict__ w2, const float* __restrict__ b2,
    float* __restrict__ bias_ws)
{
    int pair = blockIdx.x;
    int lane = threadIdx.x;
    int dy = pair / 15 - 7;
    int dx = pair % 15 - 7;
    float fy = copysignf(log1pf(fabsf((float)dy)), (float)dy);
    float fx = copysignf(log1pf(fabsf((float)dx)), (float)dx);
    int h = lane & 7;
    int j0 = lane >> 3;
    float acc = 0.0f;
    #pragma unroll 4
    for (int i = 0; i < 32; ++i) {
        int j = j0 + 8 * i;
        float t = fy * w1[j] + fx * w1[256 + j] + b1[j];
        float ge = 0.5f * t * (1.0f + erff(t * 0.70710678118654752f)); // exact GELU
        acc = fmaf(ge, w2[j * HEADS + h], acc);
    }
    acc += __shfl_xor(acc, 8, 64);
    acc += __shfl_xor(acc, 16, 64);
    acc += __shfl_xor(acc, 32, 64);
    float val = (acc + b2[h]) * 1.44269504088896341f;   // fold log2(e)

    // scatter to all (n,m) with (ny-my,nx-mx) == (dy,dx); lane covers h=lane&7,
    // ix strided by 8 across the lane>>3 groups.
    int ny0 = dy > 0 ? dy : 0;
    int nx0 = dx > 0 ? dx : 0;
    int cnty = 8 - (dy < 0 ? -dy : dy);
    int cntx = 8 - (dx < 0 ? -dx : dx);
    for (int iy = 0; iy < cnty; ++iy) {
        int ny = ny0 + iy, my = ny - dy;
        for (int ix = (lane >> 3); ix < cntx; ix += 8) {
            int nx = nx0 + ix, mx = nx - dx;
            int n = ny * 8 + nx;
            int m = my * 8 + mx;
            int nt = n >> 4, mt = m >> 4;
            int l = ((m >> 2) & 3) * 16 + (n & 15);
            int r = m & 3;
            bias_ws[(((h * 4 + mt) * 4 + nt) * 64 + l) * 4 + r] = val;
        }
    }
}

// Block = 4 heads of one window. K,V staged block-cooperatively (512-B segments);
// Q direct + per-strip prefetch; O staged in LDS f32 (overlaying dead K/V region)
// and stored block-cooperatively.  [proven best: round-10 structure, 124.3 us]
__global__ __launch_bounds__(256, 4) void win_attn_kernel(
    const float* __restrict__ qkv,
    const float* __restrict__ bias_ws,
    float* __restrict__ out)
{
    // layout: [0, 17408) K stage | [17408, 34816) V stage | [34816, 53248) P dbuf
    //         O stage f32 [64][SO] (33792 B) overlays K+V after frags are register-resident
    __shared__ __align__(16) unsigned char lds_all[53248];
    unsigned short* lds_k = (unsigned short*)lds_all;
    unsigned short* lds_v = (unsigned short*)(lds_all + 17408);
    unsigned short (*lds_p)[16][72] = (unsigned short (*)[16][72])(lds_all + 34816 + (threadIdx.x >> 6) * 4608);
    float* ostage = (float*)lds_all;

    const int tid = threadIdx.x;
    const int w = tid >> 6;
    const int l = tid & 63;
    const int c = l & 15;
    const int g = l >> 4;
    const int half = blockIdx.x & 1;
    const int b = blockIdx.x >> 1;
    const int h = half * 4 + w;                      // this wave's head
    const float* wbase = qkv + (size_t)b * (NTOK * 768);
    const float QS = 0.176776695296636893f * 1.44269504088896341f; // scale * log2(e)

    // ---- block-cooperative staging of K,V (4-head slices, bf16): 512-B segments/instr ----
    {
        const int srow0 = tid >> 5;
        const int scol  = (tid & 31) * 4;
        #pragma unroll
        for (int i = 0; i < 8; ++i) {
            int row = i * 8 + srow0;
            const float* pr = wbase + (size_t)row * 768 + half * 128 + scol;
            f32x4 kk = *(const f32x4*)(pr + 256);
            f32x4 vv = *(const f32x4*)(pr + 512);
            u32x2 kw = {cvt2(kk[0], kk[1]), cvt2(kk[2], kk[3])};
            u32x2 vw = {cvt2(vv[0], vv[1]), cvt2(vv[2], vv[3])};
            *(u32x2*)(lds_k + row * SKV + scol) = kw;
            *(u32x2*)(lds_v + row * SKV + scol) = vw;
        }
    }
    __syncthreads();

    // ---- K A-frags from LDS (b128) ----
    bf16x8 kf[4];
    #pragma unroll
    for (int t = 0; t < 4; ++t)
        kf[t] = *(const bf16x8*)(lds_k + (t * 16 + c) * SKV + w * 32 + g * 8);

    // ---- V^T A-frags: column reads (u16, once per wave) ----
    bf16x8 vf[2][2];
    #pragma unroll
    for (int ks = 0; ks < 2; ++ks)
        #pragma unroll
        for (int dt = 0; dt < 2; ++dt) {
            bf16x8 v;
            #pragma unroll
            for (int j = 0; j < 8; ++j)
                v[j] = (short)lds_v[(ks * 32 + g * 8 + j) * SKV + w * 32 + dt * 16 + c];
            vf[ks][dt] = v;
        }
    __syncthreads();   // K/V region now dead -> safe to overlay with O stage

    // Q strip 0 raw (direct; per-strip prefetch below)
    const float* qb = wbase + h * 32;
    f32x4 qraw0, qraw1;
    {
        const float* pq = qb + (size_t)c * 768 + g * 8;
        qraw0 = *(const f32x4*)(pq);
        qraw1 = *(const f32x4*)(pq + 4);
    }

    // ---- strip loop over n (nt): S^T strip -> exp2 -> P -> O^T strip -> LDS O-stage ----
    #pragma unroll
    for (int nt = 0; nt < 4; ++nt) {
        bf16x8 qf;
        {
            unsigned int q0 = cvt2(qraw0[0] * QS, qraw0[1] * QS);
            unsigned int q1 = cvt2(qraw0[2] * QS, qraw0[3] * QS);
            unsigned int q2 = cvt2(qraw1[0] * QS, qraw1[1] * QS);
            unsigned int q3 = cvt2(qraw1[2] * QS, qraw1[3] * QS);
            unsigned int qq[4] = {q0, q1, q2, q3};
            memcpy(&qf, qq, 16);
        }

        // S^T strip = K.Q^T seeded with bias frags (C-operand; L2-resident table)
        f32x4 acc[4];
        {
            const f32x4* bw = (const f32x4*)(bias_ws) + ((size_t)h * 16 + nt) * 64 + l;
            #pragma unroll
            for (int mt = 0; mt < 4; ++mt)
                acc[mt] = bw[mt * 256];
        }
        #pragma unroll
        for (int mt = 0; mt < 4; ++mt)
            acc[mt] = __builtin_amdgcn_mfma_f32_16x16x32_bf16(kf[mt], qf, acc[mt], 0, 0, 0);

        // prefetch next strip's Q while MFMAs run
        if (nt < 3) {
            const float* pq = qb + (size_t)((nt + 1) * 16 + c) * 768 + g * 8;
            qraw0 = *(const f32x4*)(pq);
            qraw1 = *(const f32x4*)(pq + 4);
        }

        // softmax numerators, no max-subtract (bounded log2-unit scores; f32-safe)
        float s = 0.0f;
        #pragma unroll
        for (int mt = 0; mt < 4; ++mt)
            #pragma unroll
            for (int r = 0; r < 4; ++r) {
                float p = __builtin_amdgcn_exp2f(acc[mt][r]);
                acc[mt][r] = p;
                s += p;
            }

        // P strip (bf16, [n][m]) -> LDS (packed cvt + b64 writes, double-buffered)
        unsigned short (*P)[72] = lds_p[nt & 1];
        #pragma unroll
        for (int mt = 0; mt < 4; ++mt) {
            unsigned int w0 = cvt2(acc[mt][0], acc[mt][1]);
            unsigned int w1 = cvt2(acc[mt][2], acc[mt][3]);
            *(u32x2*)(&P[c][mt * 16 + g * 4]) = (u32x2){w0, w1};
        }

        // cross-lane sum finish + rcp (overlaps the fence drain)
        s += __shfl_xor(s, 16, 64);
        s += __shfl_xor(s, 32, 64);
        float iv = __builtin_amdgcn_rcpf(s);

        // order: P ds_writes visible before cross-lane ds_reads
        __threadfence_block();

        // O^T strip = V^T . P^T
        f32x4 o[2];
        o[0] = (f32x4){0.f, 0.f, 0.f, 0.f};
        o[1] = (f32x4){0.f, 0.f, 0.f, 0.f};
        #pragma unroll
        for (int ks = 0; ks < 2; ++ks) {
            bf16x8 pb = *(const bf16x8*)(&P[c][ks * 32 + g * 8]);
            #pragma unroll
            for (int dt = 0; dt < 2; ++dt)
                o[dt] = __builtin_amdgcn_mfma_f32_16x16x32_bf16(vf[ks][dt], pb, o[dt], 0, 0, 0);
        }

        // normalize + write to LDS O-stage [64][SO] f32 (col ranges disjoint per wave)
        #pragma unroll
        for (int dt = 0; dt < 2; ++dt) {
            f32x4 val;
            #pragma unroll
            for (int r = 0; r < 4; ++r)
                val[r] = o[dt][r] * iv;
            *(f32x4*)(ostage + (nt * 16 + c) * SO + w * 32 + dt * 16 + g * 4) = val;
        }
    }
    __syncthreads();

    // ---- block-cooperative store: 512-B contiguous segments per wave-instruction ----
    {
        float* ob = out + (size_t)b * (NTOK * 256) + half * 128;
        const int srow0 = tid >> 5;
        const int scol  = (tid & 31) * 4;
        #pragma unroll
        for (int i = 0; i < 8; ++i) {
            int row = i * 8 + srow0;
            f32x4 val = *(const f32x4*)(ostage + row * SO + scol);
            *(f32x4*)(ob + (size_t)row * 256 + scol) = val;
        }
    }
}

extern "C" void kernel_launch(void* const* d_in, const int* in_sizes, int n_in,
                              void* d_out, int out_size, void* d_ws, size_t ws_size,
                              hipStream_t stream) {
    const float* qkv = (const float*)d_in[0];
    const float* w1  = (const float*)d_in[1];
    const float* b1  = (const float*)d_in[2];
    const float* w2  = (const float*)d_in[3];
    const float* b2  = (const float*)d_in[4];
    float* bias_ws = (float*)d_ws;   // 32768 floats = 128 KiB (proven size)

    mlp_bias_kernel<<<225, 64, 0, stream>>>(w1, b1, w2, b2, bias_ws);

    int B = in_sizes[0] / 49152;   // windows
    win_attn_kernel<<<B * 2, 256, 0, stream>>>(qkv, bias_ws, (float*)d_out);
}

// Round 14
// 109.512 us; speedup vs baseline: 1.1649x; 1.1333x over previous
//
#include <hip/hip_runtime.h>
#include <hip/hip_bf16.h>
#include <string.h>

#define NTOK 64
#define HEADS 8
#define SKV 136   // stage row stride (ushorts) = 272 B
#define SO  132   // O-stage row stride (floats) = 528 B -> 2-way-free banks

typedef __attribute__((ext_vector_type(4))) float f32x4;
typedef __attribute__((ext_vector_type(2))) unsigned int u32x2;
typedef __attribute__((ext_vector_type(8))) short bf16x8;

// packed f32x2 -> bf16x2 (RNE) -- v_cvt_pk_bf16_f32
__device__ __forceinline__ unsigned int cvt2(float a, float b) {
    __hip_bfloat162 h = __float22bfloat162_rn(float2{a, b});
    unsigned int r;
    memcpy(&r, &h, 4);
    return r;
}

// Fused prelude: one block per relative position (225). Computes the 2->256->8
// MLP for its (dy,dx), then scatters log2e*bias directly into the fragment-layout
// table bias_ws[h][mt][nt][lane][r] for every (n,m) with that offset.
__global__ __launch_bounds__(64) void mlp_bias_kernel(
    const float* __restrict__ w1, const float* __restrict__ b1,
    const float* __restrict__ w2, const float* __restrict__ b2,
    float* __restrict__ bias_ws)
{
    int pair = blockIdx.x;
    int lane = threadIdx.x;
    int dy = pair / 15 - 7;
    int dx = pair % 15 - 7;
    float fy = copysignf(log1pf(fabsf((float)dy)), (float)dy);
    float fx = copysignf(log1pf(fabsf((float)dx)), (float)dx);
    int h = lane & 7;
    int j0 = lane >> 3;
    float acc = 0.0f;
    #pragma unroll 4
    for (int i = 0; i < 32; ++i) {
        int j = j0 + 8 * i;
        float t = fy * w1[j] + fx * w1[256 + j] + b1[j];
        float ge = 0.5f * t * (1.0f + erff(t * 0.70710678118654752f)); // exact GELU
        acc = fmaf(ge, w2[j * HEADS + h], acc);
    }
    acc += __shfl_xor(acc, 8, 64);
    acc += __shfl_xor(acc, 16, 64);
    acc += __shfl_xor(acc, 32, 64);
    float val = (acc + b2[h]) * 1.44269504088896341f;   // fold log2(e)

    int ny0 = dy > 0 ? dy : 0;
    int nx0 = dx > 0 ? dx : 0;
    int cnty = 8 - (dy < 0 ? -dy : dy);
    int cntx = 8 - (dx < 0 ? -dx : dx);
    for (int iy = 0; iy < cnty; ++iy) {
        int ny = ny0 + iy, my = ny - dy;
        for (int ix = (lane >> 3); ix < cntx; ix += 8) {
            int nx = nx0 + ix, mx = nx - dx;
            int n = ny * 8 + nx;
            int m = my * 8 + mx;
            int nt = n >> 4, mt = m >> 4;
            int l = ((m >> 2) & 3) * 16 + (n & 15);
            int r = m & 3;
            bias_ws[(((h * 4 + mt) * 4 + nt) * 64 + l) * 4 + r] = val;
        }
    }
}

// Block = 4 heads of one window. K,V staged block-cooperatively (512-B segments);
// Q direct + per-strip prefetch; O staged in LDS f32 and stored block-cooperatively.
// This round: ALL HBM traffic carries nontemporal hints (zero-reuse streams).
__global__ __launch_bounds__(256, 4) void win_attn_kernel(
    const float* __restrict__ qkv,
    const float* __restrict__ bias_ws,
    float* __restrict__ out)
{
    // layout: [0, 17408) K stage | [17408, 34816) V stage | [34816, 53248) P dbuf
    //         O stage f32 [64][SO] (33792 B) overlays K+V after frags are register-resident
    __shared__ __align__(16) unsigned char lds_all[53248];
    unsigned short* lds_k = (unsigned short*)lds_all;
    unsigned short* lds_v = (unsigned short*)(lds_all + 17408);
    unsigned short (*lds_p)[16][72] = (unsigned short (*)[16][72])(lds_all + 34816 + (threadIdx.x >> 6) * 4608);
    float* ostage = (float*)lds_all;

    const int tid = threadIdx.x;
    const int w = tid >> 6;
    const int l = tid & 63;
    const int c = l & 15;
    const int g = l >> 4;
    const int half = blockIdx.x & 1;
    const int b = blockIdx.x >> 1;
    const int h = half * 4 + w;                      // this wave's head
    const float* wbase = qkv + (size_t)b * (NTOK * 768);
    const float QS = 0.176776695296636893f * 1.44269504088896341f; // scale * log2(e)

    // ---- block-cooperative staging of K,V (bf16), nontemporal loads ----
    {
        const int srow0 = tid >> 5;
        const int scol  = (tid & 31) * 4;
        #pragma unroll
        for (int i = 0; i < 8; ++i) {
            int row = i * 8 + srow0;
            const float* pr = wbase + (size_t)row * 768 + half * 128 + scol;
            f32x4 kk = __builtin_nontemporal_load((const f32x4*)(pr + 256));
            f32x4 vv = __builtin_nontemporal_load((const f32x4*)(pr + 512));
            u32x2 kw = {cvt2(kk[0], kk[1]), cvt2(kk[2], kk[3])};
            u32x2 vw = {cvt2(vv[0], vv[1]), cvt2(vv[2], vv[3])};
            *(u32x2*)(lds_k + row * SKV + scol) = kw;
            *(u32x2*)(lds_v + row * SKV + scol) = vw;
        }
    }
    __syncthreads();

    // ---- K A-frags from LDS (b128) ----
    bf16x8 kf[4];
    #pragma unroll
    for (int t = 0; t < 4; ++t)
        kf[t] = *(const bf16x8*)(lds_k + (t * 16 + c) * SKV + w * 32 + g * 8);

    // ---- V^T A-frags: column reads (u16, once per wave) ----
    bf16x8 vf[2][2];
    #pragma unroll
    for (int ks = 0; ks < 2; ++ks)
        #pragma unroll
        for (int dt = 0; dt < 2; ++dt) {
            bf16x8 v;
            #pragma unroll
            for (int j = 0; j < 8; ++j)
                v[j] = (short)lds_v[(ks * 32 + g * 8 + j) * SKV + w * 32 + dt * 16 + c];
            vf[ks][dt] = v;
        }
    __syncthreads();   // K/V region now dead -> safe to overlay with O stage

    // Q strip 0 raw (direct nontemporal; per-strip prefetch below)
    const float* qb = wbase + h * 32;
    f32x4 qraw0, qraw1;
    {
        const float* pq = qb + (size_t)c * 768 + g * 8;
        qraw0 = __builtin_nontemporal_load((const f32x4*)(pq));
        qraw1 = __builtin_nontemporal_load((const f32x4*)(pq + 4));
    }

    // ---- strip loop over n (nt): S^T strip -> exp2 -> P -> O^T strip -> LDS O-stage ----
    #pragma unroll
    for (int nt = 0; nt < 4; ++nt) {
        bf16x8 qf;
        {
            unsigned int qq[4] = {cvt2(qraw0[0] * QS, qraw0[1] * QS),
                                  cvt2(qraw0[2] * QS, qraw0[3] * QS),
                                  cvt2(qraw1[0] * QS, qraw1[1] * QS),
                                  cvt2(qraw1[2] * QS, qraw1[3] * QS)};
            memcpy(&qf, qq, 16);
        }

        // S^T strip = K.Q^T seeded with bias frags (C-operand; L2-resident table)
        f32x4 acc[4];
        {
            const f32x4* bw = (const f32x4*)(bias_ws) + ((size_t)h * 16 + nt) * 64 + l;
            #pragma unroll
            for (int mt = 0; mt < 4; ++mt)
                acc[mt] = bw[mt * 256];
        }
        #pragma unroll
        for (int mt = 0; mt < 4; ++mt)
            acc[mt] = __builtin_amdgcn_mfma_f32_16x16x32_bf16(kf[mt], qf, acc[mt], 0, 0, 0);

        // prefetch next strip's Q while MFMAs run
        if (nt < 3) {
            const float* pq = qb + (size_t)((nt + 1) * 16 + c) * 768 + g * 8;
            qraw0 = __builtin_nontemporal_load((const f32x4*)(pq));
            qraw1 = __builtin_nontemporal_load((const f32x4*)(pq + 4));
        }

        // softmax numerators, no max-subtract (bounded log2-unit scores; f32-safe)
        float s = 0.0f;
        #pragma unroll
        for (int mt = 0; mt < 4; ++mt)
            #pragma unroll
            for (int r = 0; r < 4; ++r) {
                float p = __builtin_amdgcn_exp2f(acc[mt][r]);
                acc[mt][r] = p;
                s += p;
            }

        // P strip (bf16, [n][m]) -> LDS (packed cvt + b64 writes, double-buffered)
        unsigned short (*P)[72] = lds_p[nt & 1];
        #pragma unroll
        for (int mt = 0; mt < 4; ++mt) {
            unsigned int w0 = cvt2(acc[mt][0], acc[mt][1]);
            unsigned int w1 = cvt2(acc[mt][2], acc[mt][3]);
            *(u32x2*)(&P[c][mt * 16 + g * 4]) = (u32x2){w0, w1};
        }

        // cross-lane sum finish + rcp (overlaps the fence drain)
        s += __shfl_xor(s, 16, 64);
        s += __shfl_xor(s, 32, 64);
        float iv = __builtin_amdgcn_rcpf(s);

        // order: P ds_writes visible before cross-lane ds_reads
        __threadfence_block();

        // O^T strip = V^T . P^T
        f32x4 o[2];
        o[0] = (f32x4){0.f, 0.f, 0.f, 0.f};
        o[1] = (f32x4){0.f, 0.f, 0.f, 0.f};
        #pragma unroll
        for (int ks = 0; ks < 2; ++ks) {
            bf16x8 pb = *(const bf16x8*)(&P[c][ks * 32 + g * 8]);
            #pragma unroll
            for (int dt = 0; dt < 2; ++dt)
                o[dt] = __builtin_amdgcn_mfma_f32_16x16x32_bf16(vf[ks][dt], pb, o[dt], 0, 0, 0);
        }

        // normalize + write to LDS O-stage [64][SO] f32 (col ranges disjoint per wave)
        #pragma unroll
        for (int dt = 0; dt < 2; ++dt) {
            f32x4 val;
            #pragma unroll
            for (int r = 0; r < 4; ++r)
                val[r] = o[dt][r] * iv;
            *(f32x4*)(ostage + (nt * 16 + c) * SO + w * 32 + dt * 16 + g * 4) = val;
        }
    }
    __syncthreads();

    // ---- block-cooperative store: nontemporal, 512-B contiguous per wave-instr ----
    {
        float* ob = out + (size_t)b * (NTOK * 256) + half * 128;
        const int srow0 = tid >> 5;
        const int scol  = (tid & 31) * 4;
        #pragma unroll
        for (int i = 0; i < 8; ++i) {
            int row = i * 8 + srow0;
            f32x4 val = *(const f32x4*)(ostage + row * SO + scol);
            __builtin_nontemporal_store(val, (f32x4*)(ob + (size_t)row * 256 + scol));
        }
    }
}

extern "C" void kernel_launch(void* const* d_in, const int* in_sizes, int n_in,
                              void* d_out, int out_size, void* d_ws, size_t ws_size,
                              hipStream_t stream) {
    const float* qkv = (const float*)d_in[0];
    const float* w1  = (const float*)d_in[1];
    const float* b1  = (const float*)d_in[2];
    const float* w2  = (const float*)d_in[3];
    const float* b2  = (const float*)d_in[4];
    float* bias_ws = (float*)d_ws;   // 32768 floats = 128 KiB (proven size)

    mlp_bias_kernel<<<225, 64, 0, stream>>>(w1, b1, w2, b2, bias_ws);

    int B = in_sizes[0] / 49152;   // windows
    win_attn_kernel<<<B * 2, 256, 0, stream>>>(qkv, bias_ws, (float*)d_out);
}